// Round 1
// baseline (123.209 us; speedup 1.0000x reference)
//
#include <hip/hip_runtime.h>

#define TPB 256

typedef __attribute__((ext_vector_type(8))) short bf16x8;    // 8 bf16 = 4 VGPRs
typedef __attribute__((ext_vector_type(16))) float f32x16;   // 32x32 accumulator

__device__ inline unsigned short f2bf(float f) {             // RNE fp32->bf16
    unsigned u = __float_as_uint(f);
    return (unsigned short)((u + 0x7FFFu + ((u >> 16) & 1u)) >> 16);
}
__device__ inline float bf2f(unsigned short h) {
    return __uint_as_float((unsigned)h << 16);
}
__device__ inline uint4 pack8(unsigned short s0, unsigned short s1,
                              unsigned short s2, unsigned short s3,
                              unsigned short s4, unsigned short s5,
                              unsigned short s6, unsigned short s7) {
    uint4 v;
    v.x = (unsigned)s0 | ((unsigned)s1 << 16);
    v.y = (unsigned)s2 | ((unsigned)s3 << 16);
    v.z = (unsigned)s4 | ((unsigned)s5 << 16);
    v.w = (unsigned)s6 | ((unsigned)s7 << 16);
    return v;
}
__device__ inline bf16x8 as_frag(uint4 v) {
    union { uint4 u; bf16x8 f; } c; c.u = v; return c.f;
}

// Pack each point into MFMA K=16 operand rows (logical slot = half*8 + j,
// identical convention for A and B -> k-order agnostic).
//   A (source, a=-2p): [ahx ahy ahz  alx aly alz  ahx ahy ahz  1 1 1  alx aly alz  0]
//   B (target):        [thx thy thz  thx thy thz  tlx tly tlz  wh wm wl tlx tly tlz 0]
// sum_k A*B = (ah+al).(th+tl) + |t|^2 = -2 p.t + |t|^2   (|p|^2 added in epilogue, exact fp32)
__global__ __launch_bounds__(TPB) void prep_kernel(
        const float* __restrict__ a, const float* __restrict__ b,
        uint4* __restrict__ pAa, uint4* __restrict__ pBa,   // pred: A-fmt, B-fmt
        uint4* __restrict__ pAb, uint4* __restrict__ pBb,   // targ: A-fmt, B-fmt
        float* __restrict__ norms, unsigned* __restrict__ pmins,
        float* __restrict__ acc, unsigned* __restrict__ cnt, int n) {
    int idx = blockIdx.x * TPB + threadIdx.x;
    if (idx < 2 * n) {
        int isB = idx >= n;
        int i = isB ? idx - n : idx;
        const float* s = isB ? b : a;
        float x = s[3 * i], y = s[3 * i + 1], z = s[3 * i + 2];
        float w = x * x + y * y + z * z;
        norms[idx] = w;
        // A-side: hi/lo split of -2*coords
        float ax = -2.0f * x, ay = -2.0f * y, az = -2.0f * z;
        unsigned short ahx = f2bf(ax), ahy = f2bf(ay), ahz = f2bf(az);
        unsigned short alx = f2bf(ax - bf2f(ahx));
        unsigned short aly = f2bf(ay - bf2f(ahy));
        unsigned short alz = f2bf(az - bf2f(ahz));
        // B-side: hi/lo split of coords
        unsigned short thx = f2bf(x), thy = f2bf(y), thz = f2bf(z);
        unsigned short tlx = f2bf(x - bf2f(thx));
        unsigned short tly = f2bf(y - bf2f(thy));
        unsigned short tlz = f2bf(z - bf2f(thz));
        // |t|^2 3-way split (~24 significand bits)
        unsigned short wh = f2bf(w);  float r1 = w - bf2f(wh);
        unsigned short wm = f2bf(r1); float r2 = r1 - bf2f(wm);
        unsigned short wl = f2bf(r2);
        const unsigned short ONE = 0x3F80;
        uint4* Ad = (isB ? pAb : pAa) + (size_t)i * 2;
        uint4* Bd = (isB ? pBb : pBa) + (size_t)i * 2;
        Ad[0] = pack8(ahx, ahy, ahz, alx, aly, alz, ahx, ahy);
        Ad[1] = pack8(ahz, ONE, ONE, ONE, alx, aly, alz, 0);
        Bd[0] = pack8(thx, thy, thz, thx, thy, thz, tlx, tly);
        Bd[1] = pack8(tlz, wh, wm, wl, tlx, tly, tlz, 0);
        pmins[idx] = 0xFFFFFFFFu;
    }
    if (idx == 0) { acc[0] = 0.0f; cnt[0] = 0u; }
}

// One dispatch, both directions. Block: 4 waves; wave owns 2 source groups of
// 32 rows (A-frags in regs); block covers 256 rows x 4096 targets (TS=4).
// Targets double-buffered through LDS, 128/chunk, XOR-swizzled so the
// stride-32B ds_read_b128 sits at the 8-deep bank minimum.
__global__ __launch_bounds__(TPB, 3) void minpass_kernel(
        const uint4* __restrict__ pAa, const uint4* __restrict__ pBa,
        const uint4* __restrict__ pAb, const uint4* __restrict__ pBb,
        const float* __restrict__ norms, unsigned* __restrict__ pmins, int n) {
    const int NSG = n / 256;          // 64 source blocks
    const int TS = 4;
    const int TGT = n / TS;           // 4096 targets per block
    const int NCH = TGT / 128;        // 32 chunks

    int bid = blockIdx.x;
    int dir = bid / (NSG * TS);
    int rem = bid % (NSG * TS);
    int sg = rem / TS;
    int ts = rem % TS;

    const uint4* __restrict__ Ap = dir ? pAb : pAa;
    const uint4* __restrict__ Bp = dir ? pBa : pBb;

    __shared__ uint4 buf[2][256];     // 2 x 128 targets x 32B = 8 KB

    const int tid = threadIdx.x;
    const int wid = tid >> 6, lane = tid & 63;
    const int lr = lane & 31, lh = lane >> 5;
    const int bidx = ((lr << 1) | lh) ^ ((lr >> 2) & 7);   // swizzled read slot
    const int wslot = tid ^ ((tid >> 3) & 7);              // swizzled write slot

    int row0 = sg * 256 + wid * 32 + lr;
    bf16x8 a0 = as_frag(Ap[(size_t)row0 * 2 + lh]);
    bf16x8 a1 = as_frag(Ap[(size_t)(row0 + 128) * 2 + lh]);

    float rm0[16], rm1[16];
#pragma unroll
    for (int i = 0; i < 16; ++i) { rm0[i] = __builtin_inff(); rm1[i] = __builtin_inff(); }
    f32x16 z = {};   // zero C operand, hoisted to 16 regs

    const int tbase = ts * TGT;
    uint4 pf = Bp[(size_t)tbase * 2 + tid];
    buf[0][wslot] = pf;
    __syncthreads();

    for (int ch = 0; ch < NCH; ++ch) {
        const int cur = ch & 1;
        uint4 nf;
        if (ch + 1 < NCH) nf = Bp[(size_t)(tbase + (ch + 1) * 128) * 2 + tid];
        const uint4* lb = buf[cur];
#pragma unroll
        for (int t = 0; t < 4; t += 2) {
            bf16x8 b0 = as_frag(lb[t * 64 + bidx]);
            bf16x8 b1 = as_frag(lb[t * 64 + 64 + bidx]);
            f32x16 d00 = __builtin_amdgcn_mfma_f32_32x32x16_bf16(a0, b0, z, 0, 0, 0);
            f32x16 d10 = __builtin_amdgcn_mfma_f32_32x32x16_bf16(a1, b0, z, 0, 0, 0);
            f32x16 d01 = __builtin_amdgcn_mfma_f32_32x32x16_bf16(a0, b1, z, 0, 0, 0);
            f32x16 d11 = __builtin_amdgcn_mfma_f32_32x32x16_bf16(a1, b1, z, 0, 0, 0);
#pragma unroll
            for (int i = 0; i < 16; ++i) {
                rm0[i] = fminf(rm0[i], fminf(d00[i], d01[i]));   // -> v_min3
                rm1[i] = fminf(rm1[i], fminf(d10[i], d11[i]));
            }
        }
        if (ch + 1 < NCH) buf[cur ^ 1][wslot] = nf;   // vmcnt wait auto-inserted
        __syncthreads();
    }

    // fold over the 32 columns held by this lane-half
#pragma unroll
    for (int k = 1; k < 32; k <<= 1) {
#pragma unroll
        for (int i = 0; i < 16; ++i) {
            rm0[i] = fminf(rm0[i], __shfl_xor(rm0[i], k, 64));
            rm1[i] = fminf(rm1[i], __shfl_xor(rm1[i], k, 64));
        }
    }
    if (lr == 0) {   // lanes 0 and 32: rows (i&3)+8*(i>>2)+4*lh
        unsigned* pm = pmins + (size_t)dir * n;
        const float* nb = norms + (dir ? n : 0);
        int rb = sg * 256 + wid * 32 + lh * 4;
#pragma unroll
        for (int i = 0; i < 16; ++i) {
            int r = (i & 3) + ((i >> 2) << 3);
            int r0 = rb + r, r1 = rb + 128 + r;
            // add |p|^2 exactly in fp32 after the min (monotone shift);
            // dists ~>=1e-3 >> 1e-5 error -> nonneg -> uint-monotone atomicMin
            atomicMin(&pm[r0], __float_as_uint(rm0[i] + nb[r0]));
            atomicMin(&pm[r1], __float_as_uint(rm1[i] + nb[r1]));
        }
    }
}

__global__ __launch_bounds__(TPB) void finalize_kernel(
        const uint4* __restrict__ pmins, float* __restrict__ acc,
        unsigned* __restrict__ cnt, float* __restrict__ out, int n, int nblocks) {
    int i = blockIdx.x * TPB + threadIdx.x;
    uint4 v = pmins[i];
    float sum = __uint_as_float(v.x) + __uint_as_float(v.y)
              + __uint_as_float(v.z) + __uint_as_float(v.w);
    for (int off = 32; off > 0; off >>= 1)
        sum += __shfl_down(sum, off, 64);
    __shared__ float wsum[TPB / 64];
    int lane = threadIdx.x & 63, wid = threadIdx.x >> 6;
    if (lane == 0) wsum[wid] = sum;
    __syncthreads();
    if (threadIdx.x == 0) {
        float t = 0.0f;
        for (int w = 0; w < TPB / 64; ++w) t += wsum[w];
        atomicAdd(acc, t);
        __threadfence();
        unsigned old = atomicAdd(cnt, 1u);
        if (old == (unsigned)(nblocks - 1)) {
            float a0 = atomicAdd(acc, 0.0f);
            out[0] = a0 / (float)(2 * n);
        }
    }
}

extern "C" void kernel_launch(void* const* d_in, const int* in_sizes, int n_in,
                              void* d_out, int out_size, void* d_ws, size_t ws_size,
                              hipStream_t stream) {
    const float* a = (const float*)d_in[0];
    const float* b = (const float*)d_in[1];
    int n = in_sizes[0] / 3;  // 16384
    float* out = (float*)d_out;
    char* ws = (char*)d_ws;
    float* acc = (float*)ws;                       // 1 float
    unsigned* cnt = (unsigned*)(ws + 8);           // 1 uint
    float* norms = (float*)(ws + 256);             // 2n f32 = 128 KB
    char* packs = ws + 256 + (size_t)2 * n * 4;
    size_t psz = (size_t)n * 32;                   // 512 KB per pack
    uint4* pAa = (uint4*)(packs);
    uint4* pBa = (uint4*)(packs + psz);
    uint4* pAb = (uint4*)(packs + 2 * psz);
    uint4* pBb = (uint4*)(packs + 3 * psz);
    unsigned* pmins = (unsigned*)(packs + 4 * psz);

    prep_kernel<<<(2 * n + TPB - 1) / TPB, TPB, 0, stream>>>(
        a, b, pAa, pBa, pAb, pBb, norms, pmins, acc, cnt, n);
    int mblocks = 2 * (n / 256) * 4;               // 512
    minpass_kernel<<<mblocks, TPB, 0, stream>>>(
        pAa, pBa, pAb, pBb, norms, pmins, n);
    int fblocks = (2 * n / 4) / TPB;               // 32
    finalize_kernel<<<fblocks, TPB, 0, stream>>>(
        (const uint4*)pmins, acc, cnt, out, n, fblocks);
}

// Round 2
// 101.246 us; speedup vs baseline: 1.2169x; 1.2169x over previous
//
#include <hip/hip_runtime.h>

#define TPB 256

typedef __attribute__((ext_vector_type(8))) short bf16x8;    // 8 bf16 = 4 VGPRs
typedef __attribute__((ext_vector_type(16))) float f32x16;   // 32x32 accumulator

__device__ inline unsigned short f2bf(float f) {             // RNE fp32->bf16
    unsigned u = __float_as_uint(f);
    return (unsigned short)((u + 0x7FFFu + ((u >> 16) & 1u)) >> 16);
}
__device__ inline float bf2f(unsigned short h) {
    return __uint_as_float((unsigned)h << 16);
}
__device__ inline uint4 pack8(unsigned short s0, unsigned short s1,
                              unsigned short s2, unsigned short s3,
                              unsigned short s4, unsigned short s5,
                              unsigned short s6, unsigned short s7) {
    uint4 v;
    v.x = (unsigned)s0 | ((unsigned)s1 << 16);
    v.y = (unsigned)s2 | ((unsigned)s3 << 16);
    v.z = (unsigned)s4 | ((unsigned)s5 << 16);
    v.w = (unsigned)s6 | ((unsigned)s7 << 16);
    return v;
}
__device__ inline bf16x8 as_frag(uint4 v) {
    union { uint4 u; bf16x8 f; } c; c.u = v; return c.f;
}

// Pack each point into MFMA K=16 operand rows (logical slot = half*8 + j,
// identical convention for A and B -> k-order agnostic; verified absmax=0).
//   A (source, a=-2p): [ahx ahy ahz  alx aly alz  ahx ahy ahz  1 1 1  alx aly alz  0]
//   B (target):        [thx thy thz  thx thy thz  tlx tly tlz  wh wm wl tlx tly tlz 0]
// sum_k A*B = (ah+al).(th+tl) + |t|^2 = -2 p.t + |t|^2   (|p|^2 added in epilogue, exact fp32)
__global__ __launch_bounds__(TPB) void prep_kernel(
        const float* __restrict__ a, const float* __restrict__ b,
        uint4* __restrict__ pAa, uint4* __restrict__ pBa,   // pred: A-fmt, B-fmt
        uint4* __restrict__ pAb, uint4* __restrict__ pBb,   // targ: A-fmt, B-fmt
        float* __restrict__ norms, unsigned* __restrict__ pmins,
        float* __restrict__ acc, unsigned* __restrict__ cnt, int n) {
    int idx = blockIdx.x * TPB + threadIdx.x;
    if (idx < 2 * n) {
        int isB = idx >= n;
        int i = isB ? idx - n : idx;
        const float* s = isB ? b : a;
        float x = s[3 * i], y = s[3 * i + 1], z = s[3 * i + 2];
        float w = x * x + y * y + z * z;
        norms[idx] = w;
        float ax = -2.0f * x, ay = -2.0f * y, az = -2.0f * z;
        unsigned short ahx = f2bf(ax), ahy = f2bf(ay), ahz = f2bf(az);
        unsigned short alx = f2bf(ax - bf2f(ahx));
        unsigned short aly = f2bf(ay - bf2f(ahy));
        unsigned short alz = f2bf(az - bf2f(ahz));
        unsigned short thx = f2bf(x), thy = f2bf(y), thz = f2bf(z);
        unsigned short tlx = f2bf(x - bf2f(thx));
        unsigned short tly = f2bf(y - bf2f(thy));
        unsigned short tlz = f2bf(z - bf2f(thz));
        unsigned short wh = f2bf(w);  float r1 = w - bf2f(wh);
        unsigned short wm = f2bf(r1); float r2 = r1 - bf2f(wm);
        unsigned short wl = f2bf(r2);
        const unsigned short ONE = 0x3F80;
        uint4* Ad = (isB ? pAb : pAa) + (size_t)i * 2;
        uint4* Bd = (isB ? pBb : pBa) + (size_t)i * 2;
        Ad[0] = pack8(ahx, ahy, ahz, alx, aly, alz, ahx, ahy);
        Ad[1] = pack8(ahz, ONE, ONE, ONE, alx, aly, alz, 0);
        Bd[0] = pack8(thx, thy, thz, thx, thy, thz, tlx, tly);
        Bd[1] = pack8(tlz, wh, wm, wl, tlx, tly, tlz, 0);
        pmins[idx] = 0xFFFFFFFFu;
    }
    if (idx == 0) { acc[0] = 0.0f; cnt[0] = 0u; }
}

// One dispatch, both directions. Block: 4 waves x 32 source rows each (one
// A-frag/wave resident in regs) = 128 rows; block covers 4096 targets (TS=4).
// grid = 2*128*4 = 1024 blocks = 4 blocks/CU, 16 waves/CU.
// Only 2 MFMA d-tiles in flight -> ~100 live VGPRs, fits the 128-reg cap of
// __launch_bounds__(256,4) without serialization (round-1 failure mode).
// LDS layout is linear (write slot=tid, read slot=lr*2+lh): the canonical
// conflict-free pattern; round-1's XOR swizzle caused 1M conflict cycles.
__global__ __launch_bounds__(TPB, 4) void minpass_kernel(
        const uint4* __restrict__ pAa, const uint4* __restrict__ pBa,
        const uint4* __restrict__ pAb, const uint4* __restrict__ pBb,
        const float* __restrict__ norms, unsigned* __restrict__ pmins, int n) {
    const int NSG = n / 128;          // 128 source blocks (128 rows each)
    const int TS = 4;
    const int TGT = n / TS;           // 4096 targets per block
    const int NCH = TGT / 128;        // 32 chunks of 128 targets

    int bid = blockIdx.x;
    int dir = bid / (NSG * TS);
    int rem = bid % (NSG * TS);
    int sg = rem / TS;
    int ts = rem % TS;

    const uint4* __restrict__ Ap = dir ? pAb : pAa;
    const uint4* __restrict__ Bp = dir ? pBa : pBb;

    __shared__ uint4 buf[2][256];     // 2 x 128 targets x 32B = 8 KB

    const int tid = threadIdx.x;
    const int wid = tid >> 6, lane = tid & 63;
    const int lr = lane & 31, lh = lane >> 5;
    const int rsl = (lr << 1) | lh;   // linear read slot within a 32-target tile

    int row0 = sg * 128 + wid * 32 + lr;
    bf16x8 a0 = as_frag(Ap[(size_t)row0 * 2 + lh]);

    float rm[16];
#pragma unroll
    for (int i = 0; i < 16; ++i) rm[i] = __builtin_inff();
    f32x16 z = {};   // zero C operand

    const int tbase = ts * TGT;
    uint4 pf = Bp[(size_t)tbase * 2 + tid];
    buf[0][tid] = pf;
    __syncthreads();

    for (int ch = 0; ch < NCH; ++ch) {
        const int cur = ch & 1;
        uint4 nf;
        if (ch + 1 < NCH) nf = Bp[(size_t)(tbase + (ch + 1) * 128) * 2 + tid];
        const uint4* lb = buf[cur];
#pragma unroll
        for (int t = 0; t < 4; t += 2) {
            bf16x8 b0 = as_frag(lb[t * 64 + rsl]);
            bf16x8 b1 = as_frag(lb[t * 64 + 64 + rsl]);
            f32x16 d0 = __builtin_amdgcn_mfma_f32_32x32x16_bf16(a0, b0, z, 0, 0, 0);
            f32x16 d1 = __builtin_amdgcn_mfma_f32_32x32x16_bf16(a0, b1, z, 0, 0, 0);
#pragma unroll
            for (int i = 0; i < 16; ++i)
                rm[i] = fminf(rm[i], fminf(d0[i], d1[i]));   // -> v_min3
        }
        if (ch + 1 < NCH) buf[cur ^ 1][tid] = nf;   // vmcnt wait auto-inserted
        __syncthreads();
    }

    // fold over the 32 columns held by this lane-half (stays within lh group)
#pragma unroll
    for (int k = 1; k < 32; k <<= 1) {
#pragma unroll
        for (int i = 0; i < 16; ++i)
            rm[i] = fminf(rm[i], __shfl_xor(rm[i], k, 64));
    }
    if (lr == 0) {   // lanes 0 and 32: rows (i&3)+8*(i>>2)+4*lh
        unsigned* pm = pmins + (size_t)dir * n;
        const float* nb = norms + (dir ? n : 0);
        int rb = sg * 128 + wid * 32 + lh * 4;
#pragma unroll
        for (int i = 0; i < 16; ++i) {
            int r = rb + (i & 3) + ((i >> 2) << 3);
            // add |p|^2 exactly in fp32 after the min (monotone shift);
            // nonneg floats monotone under unsigned compare -> uint atomicMin
            atomicMin(&pm[r], __float_as_uint(rm[i] + nb[r]));
        }
    }
}

__global__ __launch_bounds__(TPB) void finalize_kernel(
        const uint4* __restrict__ pmins, float* __restrict__ acc,
        unsigned* __restrict__ cnt, float* __restrict__ out, int n, int nblocks) {
    int i = blockIdx.x * TPB + threadIdx.x;
    uint4 v = pmins[i];
    float sum = __uint_as_float(v.x) + __uint_as_float(v.y)
              + __uint_as_float(v.z) + __uint_as_float(v.w);
    for (int off = 32; off > 0; off >>= 1)
        sum += __shfl_down(sum, off, 64);
    __shared__ float wsum[TPB / 64];
    int lane = threadIdx.x & 63, wid = threadIdx.x >> 6;
    if (lane == 0) wsum[wid] = sum;
    __syncthreads();
    if (threadIdx.x == 0) {
        float t = 0.0f;
        for (int w = 0; w < TPB / 64; ++w) t += wsum[w];
        atomicAdd(acc, t);
        __threadfence();
        unsigned old = atomicAdd(cnt, 1u);
        if (old == (unsigned)(nblocks - 1)) {
            float a0 = atomicAdd(acc, 0.0f);
            out[0] = a0 / (float)(2 * n);
        }
    }
}

extern "C" void kernel_launch(void* const* d_in, const int* in_sizes, int n_in,
                              void* d_out, int out_size, void* d_ws, size_t ws_size,
                              hipStream_t stream) {
    const float* a = (const float*)d_in[0];
    const float* b = (const float*)d_in[1];
    int n = in_sizes[0] / 3;  // 16384
    float* out = (float*)d_out;
    char* ws = (char*)d_ws;
    float* acc = (float*)ws;                       // 1 float
    unsigned* cnt = (unsigned*)(ws + 8);           // 1 uint
    float* norms = (float*)(ws + 256);             // 2n f32 = 128 KB
    char* packs = ws + 256 + (size_t)2 * n * 4;
    size_t psz = (size_t)n * 32;                   // 512 KB per pack
    uint4* pAa = (uint4*)(packs);
    uint4* pBa = (uint4*)(packs + psz);
    uint4* pAb = (uint4*)(packs + 2 * psz);
    uint4* pBb = (uint4*)(packs + 3 * psz);
    unsigned* pmins = (unsigned*)(packs + 4 * psz);

    prep_kernel<<<(2 * n + TPB - 1) / TPB, TPB, 0, stream>>>(
        a, b, pAa, pBa, pAb, pBb, norms, pmins, acc, cnt, n);
    int mblocks = 2 * (n / 128) * 4;               // 1024
    minpass_kernel<<<mblocks, TPB, 0, stream>>>(
        pAa, pBa, pAb, pBb, norms, pmins, n);
    int fblocks = (2 * n / 4) / TPB;               // 32
    finalize_kernel<<<fblocks, TPB, 0, stream>>>(
        (const uint4*)pmins, acc, cnt, out, n, fblocks);
}

// Round 3
// 85.644 us; speedup vs baseline: 1.4386x; 1.1822x over previous
//
#include <hip/hip_runtime.h>

#define TPB 256

typedef __attribute__((ext_vector_type(8))) short bf16x8;    // 8 bf16 = 4 VGPRs
typedef __attribute__((ext_vector_type(16))) float f32x16;   // 32x32 accumulator

__device__ inline unsigned short f2bf(float f) {             // RNE fp32->bf16
    unsigned u = __float_as_uint(f);
    return (unsigned short)((u + 0x7FFFu + ((u >> 16) & 1u)) >> 16);
}
__device__ inline float bf2f(unsigned short h) {
    return __uint_as_float((unsigned)h << 16);
}
__device__ inline uint4 pack8(unsigned short s0, unsigned short s1,
                              unsigned short s2, unsigned short s3,
                              unsigned short s4, unsigned short s5,
                              unsigned short s6, unsigned short s7) {
    uint4 v;
    v.x = (unsigned)s0 | ((unsigned)s1 << 16);
    v.y = (unsigned)s2 | ((unsigned)s3 << 16);
    v.z = (unsigned)s4 | ((unsigned)s5 << 16);
    v.w = (unsigned)s6 | ((unsigned)s7 << 16);
    return v;
}
__device__ inline bf16x8 as_frag(uint4 v) {
    union { uint4 u; bf16x8 f; } c; c.u = v; return c.f;
}

// Pack each point into MFMA K=16 operand rows (logical slot = half*8 + j,
// identical convention for A and B -> k-order agnostic; verified absmax=0).
//   A (source, a=-2p): [ahx ahy ahz  alx aly alz  ahx ahy ahz  1 1 1  alx aly alz  0]
//   B (target):        [thx thy thz  thx thy thz  tlx tly tlz  wh wm wl tlx tly tlz 0]
// sum_k A*B = (ah+al).(th+tl) + |t|^2 = -2 p.t + |t|^2   (|p|^2 added in epilogue, exact fp32)
__global__ __launch_bounds__(TPB) void prep_kernel(
        const float* __restrict__ a, const float* __restrict__ b,
        uint4* __restrict__ pAa, uint4* __restrict__ pBa,   // pred: A-fmt, B-fmt
        uint4* __restrict__ pAb, uint4* __restrict__ pBb,   // targ: A-fmt, B-fmt
        float* __restrict__ norms, unsigned* __restrict__ pmins,
        float* __restrict__ acc, unsigned* __restrict__ cnt, int n) {
    int idx = blockIdx.x * TPB + threadIdx.x;
    if (idx < 2 * n) {
        int isB = idx >= n;
        int i = isB ? idx - n : idx;
        const float* s = isB ? b : a;
        float x = s[3 * i], y = s[3 * i + 1], z = s[3 * i + 2];
        float w = x * x + y * y + z * z;
        norms[idx] = w;
        float ax = -2.0f * x, ay = -2.0f * y, az = -2.0f * z;
        unsigned short ahx = f2bf(ax), ahy = f2bf(ay), ahz = f2bf(az);
        unsigned short alx = f2bf(ax - bf2f(ahx));
        unsigned short aly = f2bf(ay - bf2f(ahy));
        unsigned short alz = f2bf(az - bf2f(ahz));
        unsigned short thx = f2bf(x), thy = f2bf(y), thz = f2bf(z);
        unsigned short tlx = f2bf(x - bf2f(thx));
        unsigned short tly = f2bf(y - bf2f(thy));
        unsigned short tlz = f2bf(z - bf2f(thz));
        unsigned short wh = f2bf(w);  float r1 = w - bf2f(wh);
        unsigned short wm = f2bf(r1); float r2 = r1 - bf2f(wm);
        unsigned short wl = f2bf(r2);
        const unsigned short ONE = 0x3F80;
        uint4* Ad = (isB ? pAb : pAa) + (size_t)i * 2;
        uint4* Bd = (isB ? pBb : pBa) + (size_t)i * 2;
        Ad[0] = pack8(ahx, ahy, ahz, alx, aly, alz, ahx, ahy);
        Ad[1] = pack8(ahz, ONE, ONE, ONE, alx, aly, alz, 0);
        Bd[0] = pack8(thx, thy, thz, thx, thy, thz, tlx, tly);
        Bd[1] = pack8(tlz, wh, wm, wl, tlx, tly, tlz, 0);
        pmins[idx] = 0xFFFFFFFFu;
    }
    if (idx == 0) { acc[0] = 0.0f; cnt[0] = 0u; }
}

// Barrier-free streaming minpass. Each wave: 64 source rows (2 resident
// A-frags), sweeps a 2048-target slice reading B-fragments DIRECTLY from
// global (B-pack is 512 KB -> L2-resident; round-2's LDS staging only saved
// re-reads that were already cache hits, and cost 64 barriers + 32 vmcnt(0)
// drains per block = the 70% stall).  4-deep rotating register prefetch:
// each load has ~3 tile-computes (~270 issue cyc) before its use.
// Block = 4 waves x 64 rows = 256 rows; TS=8 slices; grid = 2*64*8 = 1024
// blocks = 4/CU, 16 waves/CU. Only 2 d-tiles live -> ~110 VGPRs.
#define COMPUTE_TILE(X) do {                                                   \
    bf16x8 bb = as_frag(X);                                                    \
    f32x16 d0 = __builtin_amdgcn_mfma_f32_32x32x16_bf16(a0, bb, z, 0, 0, 0);   \
    f32x16 d1 = __builtin_amdgcn_mfma_f32_32x32x16_bf16(a1, bb, z, 0, 0, 0);   \
    _Pragma("unroll")                                                          \
    for (int i = 0; i < 16; ++i) {                                             \
        rm0[i] = fminf(rm0[i], d0[i]);                                         \
        rm1[i] = fminf(rm1[i], d1[i]);                                         \
    }                                                                          \
} while (0)

__global__ __launch_bounds__(TPB, 4) void minpass_kernel(
        const uint4* __restrict__ pAa, const uint4* __restrict__ pBa,
        const uint4* __restrict__ pAb, const uint4* __restrict__ pBb,
        const float* __restrict__ norms, unsigned* __restrict__ pmins, int n) {
    const int TS = 8;
    const int NRB = n / 256;          // 64 row-blocks (256 rows each)
    const int TGT = n / TS;           // 2048 targets per slice
    const int NT = TGT / 32;          // 64 B-tiles per wave

    int bid = blockIdx.x;
    int dir = bid / (NRB * TS);
    int rem = bid % (NRB * TS);
    int rbk = rem / TS;
    int ts  = rem % TS;

    const uint4* __restrict__ Ap = dir ? pAb : pAa;
    const uint4* __restrict__ Bp = dir ? pBa : pBb;

    const int tid = threadIdx.x;
    const int wid = tid >> 6, lane = tid & 63;
    const int lr = lane & 31, lh = lane >> 5;

    const int rowbase = rbk * 256 + wid * 64;
    bf16x8 a0 = as_frag(Ap[(size_t)(rowbase + lr) * 2 + lh]);
    bf16x8 a1 = as_frag(Ap[(size_t)(rowbase + 32 + lr) * 2 + lh]);

    float rm0[16], rm1[16];
#pragma unroll
    for (int i = 0; i < 16; ++i) { rm0[i] = __builtin_inff(); rm1[i] = __builtin_inff(); }
    f32x16 z = {};   // zero C operand (compiler may place in AGPRs - free)

    // lane's B-frag pointer: tile t lives at uint4-offset t*64 from here;
    // the wave's 64 lanes cover a contiguous 1KB segment (fully coalesced).
    const uint4* __restrict__ bp = Bp + (size_t)(ts * TGT + lr) * 2 + lh;

    uint4 A0 = bp[0], A1 = bp[64], A2 = bp[128], A3 = bp[192];
    for (int t = 0; t < NT - 4; t += 4) {
        COMPUTE_TILE(A0); A0 = bp[(t + 4) * 64];
        COMPUTE_TILE(A1); A1 = bp[(t + 5) * 64];
        COMPUTE_TILE(A2); A2 = bp[(t + 6) * 64];
        COMPUTE_TILE(A3); A3 = bp[(t + 7) * 64];
    }
    COMPUTE_TILE(A0); COMPUTE_TILE(A1); COMPUTE_TILE(A2); COMPUTE_TILE(A3);

    // fold over the 32 columns held by this lane-half (xor k<32 stays in half)
#pragma unroll
    for (int k = 1; k < 32; k <<= 1) {
#pragma unroll
        for (int i = 0; i < 16; ++i) {
            rm0[i] = fminf(rm0[i], __shfl_xor(rm0[i], k, 64));
            rm1[i] = fminf(rm1[i], __shfl_xor(rm1[i], k, 64));
        }
    }
    if (lr == 0) {   // lanes 0 and 32: rows (i&3)+8*(i>>2)+4*lh (+32 for a1)
        unsigned* pm = pmins + (size_t)dir * n;
        const float* nb = norms + (dir ? n : 0);
        int rb0 = rowbase + lh * 4;
#pragma unroll
        for (int i = 0; i < 16; ++i) {
            int r = (i & 3) + ((i >> 2) << 3);
            int r0 = rb0 + r, r1 = rb0 + 32 + r;
            // add |p|^2 exactly in fp32 after the min (monotone shift);
            // nonneg floats monotone under unsigned compare -> uint atomicMin
            atomicMin(&pm[r0], __float_as_uint(rm0[i] + nb[r0]));
            atomicMin(&pm[r1], __float_as_uint(rm1[i] + nb[r1]));
        }
    }
}

__global__ __launch_bounds__(TPB) void finalize_kernel(
        const uint4* __restrict__ pmins, float* __restrict__ acc,
        unsigned* __restrict__ cnt, float* __restrict__ out, int n, int nblocks) {
    int i = blockIdx.x * TPB + threadIdx.x;
    uint4 v = pmins[i];
    float sum = __uint_as_float(v.x) + __uint_as_float(v.y)
              + __uint_as_float(v.z) + __uint_as_float(v.w);
    for (int off = 32; off > 0; off >>= 1)
        sum += __shfl_down(sum, off, 64);
    __shared__ float wsum[TPB / 64];
    int lane = threadIdx.x & 63, wid = threadIdx.x >> 6;
    if (lane == 0) wsum[wid] = sum;
    __syncthreads();
    if (threadIdx.x == 0) {
        float t = 0.0f;
        for (int w = 0; w < TPB / 64; ++w) t += wsum[w];
        atomicAdd(acc, t);
        __threadfence();
        unsigned old = atomicAdd(cnt, 1u);
        if (old == (unsigned)(nblocks - 1)) {
            float a0 = atomicAdd(acc, 0.0f);
            out[0] = a0 / (float)(2 * n);
        }
    }
}

extern "C" void kernel_launch(void* const* d_in, const int* in_sizes, int n_in,
                              void* d_out, int out_size, void* d_ws, size_t ws_size,
                              hipStream_t stream) {
    const float* a = (const float*)d_in[0];
    const float* b = (const float*)d_in[1];
    int n = in_sizes[0] / 3;  // 16384
    float* out = (float*)d_out;
    char* ws = (char*)d_ws;
    float* acc = (float*)ws;                       // 1 float
    unsigned* cnt = (unsigned*)(ws + 8);           // 1 uint
    float* norms = (float*)(ws + 256);             // 2n f32 = 128 KB
    char* packs = ws + 256 + (size_t)2 * n * 4;
    size_t psz = (size_t)n * 32;                   // 512 KB per pack
    uint4* pAa = (uint4*)(packs);
    uint4* pBa = (uint4*)(packs + psz);
    uint4* pAb = (uint4*)(packs + 2 * psz);
    uint4* pBb = (uint4*)(packs + 3 * psz);
    unsigned* pmins = (unsigned*)(packs + 4 * psz);

    prep_kernel<<<(2 * n + TPB - 1) / TPB, TPB, 0, stream>>>(
        a, b, pAa, pBa, pAb, pBb, norms, pmins, acc, cnt, n);
    int mblocks = 2 * (n / 256) * 8;               // 1024
    minpass_kernel<<<mblocks, TPB, 0, stream>>>(
        pAa, pBa, pAb, pBb, norms, pmins, n);
    int fblocks = (2 * n / 4) / TPB;               // 32
    finalize_kernel<<<fblocks, TPB, 0, stream>>>(
        (const uint4*)pmins, acc, cnt, out, n, fblocks);
}